// Round 4
// baseline (92.675 us; speedup 1.0000x reference)
//
#include <hip/hip_runtime.h>
#include <math.h>

#define DIM    2048
#define NEXP   64
#define TOPK   8
#define BM     64
#define BK     64
#define NT     512
#define NTILES (DIM / BK)      // 32
#define XTILE  (BM * BK * 4)   // 16 KB
#define WTILE  16384           // 64 exp * 64 k * 2 terms * 2 B

typedef __attribute__((ext_vector_type(8)))  short bf16x8;
typedef __attribute__((ext_vector_type(16))) float f32x16;

#define MFMA(A, B, C) __builtin_amdgcn_mfma_f32_32x32x16_bf16(A, B, C, 0, 0, 0)
#define AS_BF(v) (*(const bf16x8*)&(v))

typedef __attribute__((address_space(3))) unsigned int       lds_uint;
typedef __attribute__((address_space(1))) const unsigned int glb_uint;
#define GLOAD(gp, lp) __builtin_amdgcn_global_load_lds((glb_uint*)(const void*)(gp), \
                                                       (lds_uint*)(void*)(lp), 16, 0, 0)

__device__ inline unsigned int bfpack(float a, float b) {
    unsigned int ua = __float_as_uint(a), ub = __float_as_uint(b);
    unsigned int lo = (ua + 0x7FFFu + ((ua >> 16) & 1u)) >> 16;
    unsigned int hi = (ub + 0x7FFFu + ((ub >> 16) & 1u)) & 0xFFFF0000u;
    return hi | lo;
}
__device__ inline void split2pair(float a, float b, unsigned int& h, unsigned int& m) {
    h = bfpack(a, b);
    float ra = a - __uint_as_float(h << 16);
    float rb = b - __uint_as_float(h & 0xFFFF0000u);
    m = bfpack(ra, rb);
}

// w [64][2048] f32 -> B-fragment-ordered bf16 h/m tiles:
// byte = kt*16K + ((((c32*2+s)*2+ks)*2+term)<<10) + (kh<<9) + (e5<<4)
__global__ __launch_bounds__(256) void prep_kernel(const float* __restrict__ w,
                                                   unsigned int* __restrict__ wpack,
                                                   float* __restrict__ counts) {
    const int u = blockIdx.x * 256 + threadIdx.x;   // 0..16383
    if (blockIdx.x == 0 && threadIdx.x < NEXP) counts[threadIdx.x] = 0.0f;
    const int e = u >> 8, k8 = u & 255;
    const float4 v0 = *(const float4*)(w + (size_t)e * DIM + k8 * 8);
    const float4 v1 = *(const float4*)(w + (size_t)e * DIM + k8 * 8 + 4);
    unsigned int h[4], m[4];
    split2pair(v0.x, v0.y, h[0], m[0]);
    split2pair(v0.z, v0.w, h[1], m[1]);
    split2pair(v1.x, v1.y, h[2], m[2]);
    split2pair(v1.z, v1.w, h[3], m[3]);
    const int kt = k8 >> 3, r3 = k8 & 7;
    const int s = r3 >> 2, ks = (r3 >> 1) & 1, kh = r3 & 1;
    const int c32 = e >> 5, e5 = e & 31;
    char* base = (char*)wpack + (size_t)kt * WTILE + (kh << 9) + (e5 << 4);
    *(uint4*)(base + (((((c32 * 2 + s) * 2 + ks) * 2) + 0) << 10)) = (uint4){h[0], h[1], h[2], h[3]};
    *(uint4*)(base + (((((c32 * 2 + s) * 2 + ks) * 2) + 1) << 10)) = (uint4){m[0], m[1], m[2], m[3]};
}

__global__ __launch_bounds__(NT, 1) void router_kernel(
    const float* __restrict__ x,
    const unsigned int* __restrict__ wpack,
    const float* __restrict__ bias,
    float* __restrict__ out,   // [M*8] scores | [M*8] idx(f32) | [64] counts(f32)
    int M)
{
    __shared__ __align__(16) char xs[3][XTILE];
    __shared__ __align__(16) char wsb[3][WTILE];
    __shared__ int hist[NEXP];

    const int tid  = threadIdx.x;
    const int wv   = tid >> 6;
    const int lane = tid & 63;
    const int row0 = blockIdx.x * BM;
    if (tid < NEXP) hist[tid] = 0;

    // ---- x stage mapping: linear LDS dest granule Gd -> (row, slot); data granule = slot^(row&7)
    const int Gd0 = wv * 64 + lane;
    const int r0  = Gd0 >> 4, g0 = (Gd0 & 15) ^ (r0 & 7);
    const int Gd1 = 512 + Gd0;
    const int r1  = Gd1 >> 4, g1 = (Gd1 & 15) ^ (r1 & 7);
    const float* xsrc0 = x + (size_t)(row0 + r0) * DIM + g0 * 4;
    const float* xsrc1 = x + (size_t)(row0 + r1) * DIM + g1 * 4;
    // ---- w stage: pure linear copy
    const unsigned int* wsrc = wpack + (wv << 8) + (lane << 2);

#define STAGE(kt, b)                                              \
    do {                                                          \
        GLOAD(xsrc0 + (kt) * BK, &xs[b][(wv) << 10]);             \
        GLOAD(xsrc1 + (kt) * BK, &xs[b][8192 + ((wv) << 10)]);    \
        GLOAD(wsrc + (kt) * 4096, &wsb[b][(wv) << 10]);           \
        GLOAD(wsrc + (kt) * 4096 + 2048, &wsb[b][8192 + ((wv) << 10)]); \
    } while (0)

    // ---- compute roles: 8 waves = 4 tiles (2x2) x split-K-2
    const int s    = wv >> 2;
    const int tile = wv & 3;
    const int trow = (tile >> 1) * 32;
    const int c32  = tile & 1;
    const int tcol = c32 * 32;
    const int lr   = lane & 31;
    const int kh   = lane >> 5;
    const int arow = trow + lr;
    const int axor = arow & 7;
    const int aoff = arow * 256;
    const int wboff = (c32 * 2 + s) * 4096 + (kh << 9) + (lr << 4);
    const float biasv = bias[tcol + lr];

    f32x16 acc = {};

    STAGE(0, 0); STAGE(1, 1); STAGE(2, 2);

    for (int t = 0; t < NTILES; ++t) {
        if (t < NTILES - 2)       asm volatile("s_waitcnt vmcnt(8)" ::: "memory");
        else if (t == NTILES - 2) asm volatile("s_waitcnt vmcnt(4)" ::: "memory");
        else                      asm volatile("s_waitcnt vmcnt(0)" ::: "memory");
        __builtin_amdgcn_sched_barrier(0);
        __builtin_amdgcn_s_barrier();

        const int b = t % 3;
        const char* xb = &xs[b][0];
        const char* wb = &wsb[b][0];
        #pragma unroll
        for (int ks = 0; ks < 2; ++ks) {
            const int ga = s * 8 + ks * 4 + kh * 2;
            float4 a0 = *(const float4*)(xb + aoff + (((ga + 0) ^ axor) << 4));
            float4 a1 = *(const float4*)(xb + aoff + (((ga + 1) ^ axor) << 4));
            unsigned int ah[4], am[4];
            split2pair(a0.x, a0.y, ah[0], am[0]);
            split2pair(a0.z, a0.w, ah[1], am[1]);
            split2pair(a1.x, a1.y, ah[2], am[2]);
            split2pair(a1.z, a1.w, ah[3], am[3]);
            const uint4 ahv = (uint4){ah[0], ah[1], ah[2], ah[3]};
            const uint4 amv = (uint4){am[0], am[1], am[2], am[3]};
            const uint4 bh = *(const uint4*)(wb + wboff + (ks << 11));
            const uint4 bm = *(const uint4*)(wb + wboff + (ks << 11) + 1024);
            acc = MFMA(AS_BF(ahv), AS_BF(bh), acc);
            acc = MFMA(AS_BF(amv), AS_BF(bh), acc);
            acc = MFMA(AS_BF(ahv), AS_BF(bm), acc);
        }
        asm volatile("s_waitcnt lgkmcnt(0)" ::: "memory");
        __builtin_amdgcn_sched_barrier(0);
        __builtin_amdgcn_s_barrier();
        if (t + 3 < NTILES) STAGE(t + 3, b);
    }

    __syncthreads();

    // ---- split-K reduce + bias (reuse x staging LDS as lg[64][66])
    float* lg = (float*)&xs[0][0];
    if (s == 0) {
        #pragma unroll
        for (int r = 0; r < 16; ++r) {
            const int rr = (r & 3) + 8 * (r >> 2) + 4 * kh;   // verified C-layout
            lg[(trow + rr) * 66 + tcol + lr] = acc[r];
        }
    }
    __syncthreads();
    if (s == 1) {
        #pragma unroll
        for (int r = 0; r < 16; ++r) {
            const int rr = (r & 3) + 8 * (r >> 2) + 4 * kh;
            const int idx = (trow + rr) * 66 + tcol + lr;
            lg[idx] = lg[idx] + acc[r] + biasv;
        }
    }
    __syncthreads();

    // ---- top-k + softmax + histogram (verified epilogue)
    float* out_scores = out;
    float* out_idx    = out + (size_t)M * TOPK;
    float* out_counts = out + (size_t)2 * M * TOPK;

    for (int r8 = 0; r8 < 8; ++r8) {
        const int row = wv * 8 + r8;
        float vm = lg[row * 66 + lane];
        float vals[TOPK];
        int   ids[TOPK];
        #pragma unroll
        for (int k = 0; k < TOPK; ++k) {
            float mv = vm;
            int   mi = lane;
            #pragma unroll
            for (int off = 32; off > 0; off >>= 1) {
                float ov = __shfl_xor(mv, off);
                int   oi = __shfl_xor(mi, off);
                if (ov > mv || (ov == mv && oi < mi)) { mv = ov; mi = oi; }
            }
            vals[k] = mv; ids[k] = mi;
            if (lane == mi) { vm = -INFINITY; atomicAdd(&hist[mi], 1); }
        }
        if (lane == 0) {
            const float m = vals[0];
            float e[TOPK];
            float ssum = 0.f;
            #pragma unroll
            for (int k = 0; k < TOPK; ++k) { e[k] = expf(vals[k] - m); ssum += e[k]; }
            const float inv = 1.0f / ssum;
            const size_t base = (size_t)(row0 + row) * TOPK;
            #pragma unroll
            for (int k = 0; k < TOPK; ++k) {
                out_scores[base + k] = e[k] * inv;
                out_idx[base + k]    = (float)ids[k];
            }
        }
    }

    __syncthreads();
    if (tid < NEXP) atomicAdd(&out_counts[tid], (float)hist[tid]);
#undef STAGE
}

extern "C" void kernel_launch(void* const* d_in, const int* in_sizes, int n_in,
                              void* d_out, int out_size, void* d_ws, size_t ws_size,
                              hipStream_t stream) {
    const float* x    = (const float*)d_in[0];
    const float* w    = (const float*)d_in[1];
    const float* bias = (const float*)d_in[2];
    float* out = (float*)d_out;
    const int M = in_sizes[0] / DIM;   // 16384 rows

    unsigned int* wpack = (unsigned int*)d_ws;   // 512 KB
    float* out_counts = out + (size_t)2 * M * TOPK;

    prep_kernel<<<64, 256, 0, stream>>>(w, wpack, out_counts);
    router_kernel<<<M / BM, NT, 0, stream>>>(x, wpack, bias, out, M);
}

// Round 5
// 92.143 us; speedup vs baseline: 1.0058x; 1.0058x over previous
//
#include <hip/hip_runtime.h>
#include <math.h>

#define DIM   2048
#define NEXP  64
#define TOPK  8
#define ROWS  32            // rows per block
#define NT    512           // 8 waves: split-K-8
#define KW    (DIM / 8)     // 256 k per wave
#define STEPS (KW / 16)     // 16 K16-steps per wave
#define NBLK  512           // M / ROWS

typedef __attribute__((ext_vector_type(8)))  short bf16x8;
typedef __attribute__((ext_vector_type(16))) float f32x16;

#define MFMA(A, B, C) __builtin_amdgcn_mfma_f32_32x32x16_bf16(A, B, C, 0, 0, 0)
#define AS_BF(v) (*(const bf16x8*)&(v))

__device__ inline unsigned int bfpack(float a, float b) {
    unsigned int ua = __float_as_uint(a), ub = __float_as_uint(b);
    unsigned int lo = (ua + 0x7FFFu + ((ua >> 16) & 1u)) >> 16;
    unsigned int hi = (ub + 0x7FFFu + ((ub >> 16) & 1u)) & 0xFFFF0000u;
    return hi | lo;
}
__device__ inline void split2pair(float a, float b, unsigned int& h, unsigned int& m) {
    h = bfpack(a, b);
    float ra = a - __uint_as_float(h << 16);
    float rb = b - __uint_as_float(h & 0xFFFF0000u);
    m = bfpack(ra, rb);
}

// w [64][2048] f32 -> per-lane 64B-contiguous step groups:
// byte = (((lr*2 + kh)*8 + wv)*16 + t)*64 + (c32*32) + term*16
//   where e=(c32,lr), k8 = wv*32 + 2t + kh
__global__ __launch_bounds__(256) void prep_kernel(const float* __restrict__ w,
                                                   unsigned int* __restrict__ wpack) {
    const int u = blockIdx.x * 256 + threadIdx.x;   // 0..16383
    const int e = u >> 8, k8 = u & 255;
    const float4 v0 = *(const float4*)(w + (size_t)e * DIM + k8 * 8);
    const float4 v1 = *(const float4*)(w + (size_t)e * DIM + k8 * 8 + 4);
    unsigned int h[4], m[4];
    split2pair(v0.x, v0.y, h[0], m[0]);
    split2pair(v0.z, v0.w, h[1], m[1]);
    split2pair(v1.x, v1.y, h[2], m[2]);
    split2pair(v1.z, v1.w, h[3], m[3]);
    const int lr = e & 31, c32 = e >> 5;
    const int wv = k8 >> 5, r = k8 & 31, t = r >> 1, kh = r & 1;
    char* base = (char*)wpack + ((((size_t)(lr * 2 + kh) * 8 + wv) * 16 + t) << 6) + c32 * 32;
    *(uint4*)(base)      = (uint4){h[0], h[1], h[2], h[3]};
    *(uint4*)(base + 16) = (uint4){m[0], m[1], m[2], m[3]};
}

__global__ __launch_bounds__(NT, 4) void router_kernel(
    const float* __restrict__ x,
    const unsigned int* __restrict__ wpack,
    const float* __restrict__ bias,
    float* __restrict__ out,     // [M*8] scores | [M*8] idx(f32) | [64] counts(f32)
    int* __restrict__ histws,    // [NBLK][64]
    int M)
{
    __shared__ float lg[8][ROWS][NEXP + 2];
    __shared__ int   hist[NEXP];

    const int tid  = threadIdx.x;
    const int wv   = tid >> 6;          // 0..7 : K-slice
    const int lane = tid & 63;
    const int lr   = lane & 31;
    const int kh   = lane >> 5;
    // bijective XCD swizzle: each XCD gets a contiguous 64-stripe (16 MB) span
    const int bid  = blockIdx.x;
    const int swz  = (bid & 7) * (NBLK / 8) + (bid >> 3);
    const int row0 = swz * ROWS;
    if (tid < NEXP) hist[tid] = 0;

    const float* xp = x + (size_t)(row0 + lr) * DIM + wv * KW + kh * 8;
    const char* wstream = (const char*)wpack + (((size_t)(lr * 2 + kh) * 8 + wv) << 10);

    f32x16 acc0 = {}, acc1 = {};

    float4 xa[2], xb[2];
    uint4  h0[2], m0[2], h1[2], m1[2];

#define LOADSTEP(s, t)                                          \
    do {                                                        \
        xa[s] = *(const float4*)(xp + (t) * 16);                \
        xb[s] = *(const float4*)(xp + (t) * 16 + 4);            \
        const uint4* wp = (const uint4*)(wstream + (t) * 64);   \
        h0[s] = wp[0]; m0[s] = wp[1]; h1[s] = wp[2]; m1[s] = wp[3]; \
    } while (0)

    LOADSTEP(0, 0);
    LOADSTEP(1, 1);

    #pragma unroll
    for (int t = 0; t < STEPS; ++t) {
        const int s = t & 1;
        unsigned int ah[4], am[4];
        split2pair(xa[s].x, xa[s].y, ah[0], am[0]);
        split2pair(xa[s].z, xa[s].w, ah[1], am[1]);
        split2pair(xb[s].x, xb[s].y, ah[2], am[2]);
        split2pair(xb[s].z, xb[s].w, ah[3], am[3]);
        const uint4 ahv = (uint4){ah[0], ah[1], ah[2], ah[3]};
        const uint4 amv = (uint4){am[0], am[1], am[2], am[3]};
        const uint4 bh0 = h0[s], bm0 = m0[s], bh1 = h1[s], bm1 = m1[s];
        if (t + 2 < STEPS) LOADSTEP(s, t + 2);
        acc0 = MFMA(AS_BF(ahv), AS_BF(bh0), acc0);
        acc1 = MFMA(AS_BF(ahv), AS_BF(bh1), acc1);
        acc0 = MFMA(AS_BF(amv), AS_BF(bh0), acc0);
        acc1 = MFMA(AS_BF(amv), AS_BF(bh1), acc1);
        acc0 = MFMA(AS_BF(ahv), AS_BF(bm0), acc0);
        acc1 = MFMA(AS_BF(ahv), AS_BF(bm1), acc1);
    }
#undef LOADSTEP

    // split-K partials to LDS
    #pragma unroll
    for (int r = 0; r < 16; ++r) {
        const int rr = (r & 3) + 8 * (r >> 2) + 4 * kh;   // verified C-layout (m74/m101)
        lg[wv][rr][lr]      = acc0[r];
        lg[wv][rr][32 + lr] = acc1[r];
    }
    __syncthreads();

    float* out_scores = out;
    float* out_idx    = out + (size_t)M * TOPK;

    // each wave: 4 rows; lane = expert
    #pragma unroll
    for (int i = 0; i < 4; ++i) {
        const int row = wv * 4 + i;
        float vm = bias[lane];
        #pragma unroll
        for (int p = 0; p < 8; ++p) vm += lg[p][row][lane];

        float vals[TOPK];
        int   ids[TOPK];
        #pragma unroll
        for (int k = 0; k < TOPK; ++k) {
            float mv = vm;
            int   mi = lane;
            #pragma unroll
            for (int off = 32; off > 0; off >>= 1) {
                float ov = __shfl_xor(mv, off);
                int   oi = __shfl_xor(mi, off);
                if (ov > mv || (ov == mv && oi < mi)) { mv = ov; mi = oi; }
            }
            vals[k] = mv; ids[k] = mi;
            if (lane == mi) { vm = -INFINITY; atomicAdd(&hist[mi], 1); }
        }
        if (lane == 0) {
            const float m = vals[0];
            float e[TOPK];
            float ssum = 0.f;
            #pragma unroll
            for (int k = 0; k < TOPK; ++k) { e[k] = expf(vals[k] - m); ssum += e[k]; }
            const float inv = 1.0f / ssum;
            const size_t base = (size_t)(row0 + row) * TOPK;
            #pragma unroll
            for (int k = 0; k < TOPK; ++k) {
                out_scores[base + k] = e[k] * inv;
                out_idx[base + k]    = (float)ids[k];
            }
        }
    }

    __syncthreads();
    if (tid < NEXP) histws[bid * NEXP + tid] = hist[tid];   // no global atomics
}

// sum per-block histograms -> counts (written as float)
__global__ __launch_bounds__(512) void reduce_kernel(const int* __restrict__ histws,
                                                     float* __restrict__ counts) {
    __shared__ int part[8][NEXP];
    const int t = threadIdx.x;
    const int e = t & 63, c = t >> 6;
    int s = 0;
    for (int b = c; b < NBLK; b += 8) s += histws[b * NEXP + e];
    part[c][e] = s;
    __syncthreads();
    if (t < NEXP) {
        int tot = 0;
        #pragma unroll
        for (int i = 0; i < 8; ++i) tot += part[i][t];
        counts[t] = (float)tot;
    }
}

extern "C" void kernel_launch(void* const* d_in, const int* in_sizes, int n_in,
                              void* d_out, int out_size, void* d_ws, size_t ws_size,
                              hipStream_t stream) {
    const float* x    = (const float*)d_in[0];
    const float* w    = (const float*)d_in[1];
    const float* bias = (const float*)d_in[2];
    float* out = (float*)d_out;
    const int M = in_sizes[0] / DIM;   // 16384 rows

    unsigned int* wpack = (unsigned int*)d_ws;                      // 512 KB
    int* histws = (int*)((char*)d_ws + (size_t)NEXP * DIM * 4);     // 128 KB
    float* out_counts = out + (size_t)2 * M * TOPK;

    prep_kernel<<<64, 256, 0, stream>>>(w, wpack);
    router_kernel<<<NBLK, NT, 0, stream>>>(x, wpack, bias, out, histws, M);
    reduce_kernel<<<1, 512, 0, stream>>>(histws, out_counts);
}